// Round 10
// baseline (213.704 us; speedup 1.0000x reference)
//
#include <hip/hip_runtime.h>
#include <hip/hip_bf16.h>
#include <math.h>

#define S_LEN 2048
#define BATCH 2
#define EDIM 1024
#define NH 16
#define HD 64
#define MTOK (S_LEN * BATCH)   // 4096 tokens
#define SCALE 0.125f           // 64^-0.5
#define LOG2E 1.4426950408889634f
#define EPS 1e-6f

typedef __bf16 bf16x8 __attribute__((ext_vector_type(8)));
typedef __bf16 bf16x4 __attribute__((ext_vector_type(4)));
typedef float f32x4 __attribute__((ext_vector_type(4)));

typedef __attribute__((address_space(3))) void lds_void;
typedef const __attribute__((address_space(1))) void gbl_void;
#define GLOAD_LDS16(g, l) \
    __builtin_amdgcn_global_load_lds((gbl_void*)(g), (lds_void*)(l), 16, 0, 0)

// All bf16 GEMM operand buffers use the "row-rotation" layout: within each
// aligned 64-col block of row m, element at col c is stored at
// (c & ~63) | ((c + (m&7)*8) & 63). GEMM frag reads apply the inverse
// (rot=(lo&7)*8) -> LDS reads are 2-way (free, m136) instead of 16-way.

// ---------------------------------------------------------------------------
// cast_all (unchanged; zeroes sumsq which attn_v12 atomically accumulates)
// ---------------------------------------------------------------------------
__global__ __launch_bounds__(256) void cast_all(const float* __restrict__ x,
                                                const float* __restrict__ Wq,
                                                const float* __restrict__ Wk,
                                                const float* __restrict__ Wv,
                                                const float* __restrict__ Wo,
                                                const float* __restrict__ nw,
                                                __bf16* __restrict__ xb,
                                                __bf16* __restrict__ Wqkvb,
                                                __bf16* __restrict__ Wob,
                                                float* __restrict__ sumsq) {
    int gt = blockIdx.x * 256 + threadIdx.x;
    if (gt < 1024) ((float4*)sumsq)[gt] = (float4){0.f, 0.f, 0.f, 0.f};
    int i = gt * 8;

    const float* src;
    __bf16* dstbase;
    int row, c;
    bool isWo = false;
    if (i < (MTOK * EDIM)) {
        src = x + i;
        row = i >> 10; c = i & 1023;
        dstbase = xb + ((size_t)row << 10);
    } else {
        int j = i - MTOK * EDIM;
        int seg = j >> 20;
        int off = j & 0xFFFFF;
        src = ((seg == 0) ? Wq : (seg == 1) ? Wk : (seg == 2) ? Wv : Wo) + off;
        row = off >> 10; c = off & 1023;
        if (seg < 3) { dstbase = Wqkvb + ((size_t)(j >> 10) << 10); }
        else         { dstbase = Wob + ((size_t)row << 10); isWo = true; }
    }
    float4 a = *(const float4*)(src);
    float4 b = *(const float4*)(src + 4);
    if (isWo) {
        float4 na = *(const float4*)(nw + c);
        float4 nb = *(const float4*)(nw + c + 4);
        a.x *= na.x; a.y *= na.y; a.z *= na.z; a.w *= na.w;
        b.x *= nb.x; b.y *= nb.y; b.z *= nb.z; b.w *= nb.w;
    }
    bf16x8 o;
    o[0] = (__bf16)a.x; o[1] = (__bf16)a.y; o[2] = (__bf16)a.z; o[3] = (__bf16)a.w;
    o[4] = (__bf16)b.x; o[5] = (__bf16)b.y; o[6] = (__bf16)b.z; o[7] = (__bf16)b.w;
    int rot = (row & 7) * 8;
    int cp = (c & ~63) | ((c + rot) & 63);
    *(bf16x8*)(dstbase + cp) = o;
}

// ---------------------------------------------------------------------------
// QKV GEMM v2 (unchanged from R2): 256x256 8-phase counted-vmcnt; q epilogue
// folds LOG2E into SCALE so attention uses raw v_exp_f32 (2^x).
// ---------------------------------------------------------------------------
#define BARRIER __builtin_amdgcn_s_barrier()
#define LGKM0 do { asm volatile("s_waitcnt lgkmcnt(0)" ::: "memory"); \
                   __builtin_amdgcn_sched_barrier(0); } while (0)
#define SETP(x) __builtin_amdgcn_s_setprio(x)

__global__ __launch_bounds__(512, 2) void gemm_qkv(const __bf16* __restrict__ A,
                                                   const __bf16* __restrict__ W,
                                                   const float* __restrict__ bias0,
                                                   const float* __restrict__ bias1,
                                                   const float* __restrict__ bias2,
                                                   __bf16* __restrict__ qb,
                                                   __bf16* __restrict__ kb,
                                                   __bf16* __restrict__ vT,
                                                   const float* __restrict__ cosT,
                                                   const float* __restrict__ sinT) {
    // [buf0.A 256x64 | buf0.B 256x64 | buf1.A 256x64 | buf1.B 256x64]
    __shared__ __bf16 SMEM[4 * 256 * 64];   // 128 KiB

    const int tid  = threadIdx.x;
    const int w    = tid >> 6;       // 0..7
    const int lane = tid & 63;
    const int quad = lane >> 4;
    const int lo   = lane & 15;
    const int wr   = w >> 2;         // M-wave 0..1 (128 rows each)
    const int wc   = w & 3;          // N-wave 0..3 (64 cols each = one head)
    const int m0 = blockIdx.y * 256;
    const int n0 = blockIdx.x * 256;

    f32x4 acc[8][4];
#pragma unroll
    for (int i = 0; i < 8; ++i)
#pragma unroll
        for (int j = 0; j < 4; ++j) acc[i][j] = (f32x4){0.f, 0.f, 0.f, 0.f};

    // staging: 512 threads, lane-linear LDS dest (wave-uniform base + lane*16)
    const int srow = tid >> 3;            // 0..63
    const int scol = (tid & 7) * 8;       // 0..56
    const __bf16* Ag = A + (size_t)(m0 + srow) * EDIM + scol;
    const __bf16* Bg = W + (size_t)(n0 + srow) * EDIM + scol;
    __bf16* ldsA0 = SMEM + srow * 64 + scol;
    __bf16* ldsB0 = SMEM + 16384 + srow * 64 + scol;

#define STAGE_A(b, h, kt) do { \
    GLOAD_LDS16(Ag + (size_t)((h) * 131072 + (kt) * 64),         ldsA0 + (b) * 32768 + (h) * 8192); \
    GLOAD_LDS16(Ag + (size_t)((h) * 131072 + 65536 + (kt) * 64), ldsA0 + (b) * 32768 + (h) * 8192 + 4096); } while (0)
#define STAGE_B(b, h, kt) do { \
    GLOAD_LDS16(Bg + (size_t)((h) * 131072 + (kt) * 64),         ldsB0 + (b) * 32768 + (h) * 8192); \
    GLOAD_LDS16(Bg + (size_t)((h) * 131072 + 65536 + (kt) * 64), ldsB0 + (b) * 32768 + (h) * 8192 + 4096); } while (0)

    // fragment reads (inverse row-rotation; row&7 == lo&7 since bases %16==0)
    const int rotc = (lo & 7) * 8;
    const int c0 = (quad * 8 + rotc) & 63;          // kk=0
    const int c1 = (32 + quad * 8 + rotc) & 63;     // kk=1
    const __bf16* Arow = SMEM + (wr * 128 + lo) * 64;
    const __bf16* Brow = SMEM + 16384 + (wc * 64 + lo) * 64;

    bf16x8 af[4][2], bf0[2][2], bf1[2][2];

#define READ_AF(b, mh) do { _Pragma("unroll") for (int i = 0; i < 4; ++i) { \
    af[i][0] = *(const bf16x8*)&Arow[(b) * 32768 + ((mh) * 4 + i) * 1024 + c0]; \
    af[i][1] = *(const bf16x8*)&Arow[(b) * 32768 + ((mh) * 4 + i) * 1024 + c1]; } } while (0)
#define READ_BF(b, nh, dst) do { _Pragma("unroll") for (int j = 0; j < 2; ++j) { \
    dst[j][0] = *(const bf16x8*)&Brow[(b) * 32768 + ((nh) * 2 + j) * 1024 + c0]; \
    dst[j][1] = *(const bf16x8*)&Brow[(b) * 32768 + ((nh) * 2 + j) * 1024 + c1]; } } while (0)

#define MFMA_Q(mh, nh, BF) do { \
    _Pragma("unroll") for (int i = 0; i < 4; ++i) \
    _Pragma("unroll") for (int j = 0; j < 2; ++j) { \
        acc[(mh)*4+i][(nh)*2+j] = __builtin_amdgcn_mfma_f32_16x16x32_bf16( \
            af[i][0], BF[j][0], acc[(mh)*4+i][(nh)*2+j], 0, 0, 0); \
        acc[(mh)*4+i][(nh)*2+j] = __builtin_amdgcn_mfma_f32_16x16x32_bf16( \
            af[i][1], BF[j][1], acc[(mh)*4+i][(nh)*2+j], 0, 0, 0); } } while (0)

#define ITER(ST, T0) do { \
    /* P1: quadrant (mh0,nh0) of tile T0 (buf0) */ \
    READ_AF(0, 0); READ_BF(0, 0, bf0); \
    BARRIER; LGKM0; SETP(1); MFMA_Q(0, 0, bf0); SETP(0); BARRIER; \
    /* P2: (mh0,nh1) */ \
    READ_BF(0, 1, bf1); \
    BARRIER; LGKM0; SETP(1); MFMA_Q(0, 1, bf1); SETP(0); BARRIER; \
    /* P3: (mh1,nh1); stage B0(T0+2) */ \
    READ_AF(0, 1); \
    if (ST) STAGE_B(0, 0, (T0) + 2); \
    BARRIER; LGKM0; SETP(1); MFMA_Q(1, 1, bf1); SETP(0); BARRIER; \
    /* P4: (mh1,nh0); stage B1,A0(T0+2); counted vmcnt */ \
    if (ST) { STAGE_B(0, 1, (T0) + 2); STAGE_A(0, 0, (T0) + 2); } \
    BARRIER; SETP(1); MFMA_Q(1, 0, bf0); SETP(0); \
    if (ST) { asm volatile("s_waitcnt vmcnt(6)" ::: "memory"); } \
    else    { asm volatile("s_waitcnt vmcnt(0)" ::: "memory"); } \
    BARRIER; \
    /* P5: (mh0,nh0) of tile T0+1 (buf1); stage A1(T0+2) */ \
    READ_AF(1, 0); READ_BF(1, 0, bf0); \
    if (ST) STAGE_A(0, 1, (T0) + 2); \
    BARRIER; LGKM0; SETP(1); MFMA_Q(0, 0, bf0); SETP(0); BARRIER; \
    /* P6: (mh0,nh1) */ \
    READ_BF(1, 1, bf1); \
    BARRIER; LGKM0; SETP(1); MFMA_Q(0, 1, bf1); SETP(0); BARRIER; \
    /* P7: (mh1,nh1); stage B0(T0+3) */ \
    READ_AF(1, 1); \
    if (ST) STAGE_B(1, 0, (T0) + 3); \
    BARRIER; LGKM0; SETP(1); MFMA_Q(1, 1, bf1); SETP(0); BARRIER; \
    /* P8: (mh1,nh0); stage B1,A0,A1(T0+3); counted vmcnt */ \
    if (ST) { STAGE_B(1, 1, (T0) + 3); STAGE_A(1, 0, (T0) + 3); STAGE_A(1, 1, (T0) + 3); } \
    BARRIER; SETP(1); MFMA_Q(1, 0, bf0); SETP(0); \
    if (ST) { asm volatile("s_waitcnt vmcnt(8)" ::: "memory"); } \
    BARRIER; \
} while (0)

    // prologue: tile0 -> buf0 (oldest 8 loads), tile1 -> buf1; keep tile1 in flight
    STAGE_A(0, 0, 0); STAGE_A(0, 1, 0); STAGE_B(0, 0, 0); STAGE_B(0, 1, 0);
    STAGE_A(1, 0, 1); STAGE_A(1, 1, 1); STAGE_B(1, 0, 1); STAGE_B(1, 1, 1);
    asm volatile("s_waitcnt vmcnt(8)" ::: "memory");
    BARRIER;

#pragma unroll 1
    for (int p = 0; p < 7; ++p) { ITER(1, 2 * p); }
    ITER(0, 14);

    // ------------------------- epilogues -------------------------
    const int seg = n0 >> 10;                 // block-uniform (256 | 1024)
    const int colbase = (n0 & 1023) + wc * 64;

    if (seg < 2) {
        // fused RoPE: wave covers one head (64 cols)
        const float* bp = (seg == 0) ? bias0 : bias1;
        __bf16* dstb = (seg == 0) ? qb : kb;
        const int h = colbase >> 6;
        float b0v = bp[colbase + lo];
        float b1v = bp[colbase + 16 + lo];
        float b2v = bp[colbase + 32 + lo];
        float b3v = bp[colbase + 48 + lo];
#pragma unroll
        for (int mt = 0; mt < 8; ++mt) {
#pragma unroll
            for (int r = 0; r < 4; ++r) {
                const int m = m0 + wr * 128 + mt * 16 + quad * 4 + r;
                const int s = m >> 1, bidx = m & 1;
                float x0 = acc[mt][0][r] + b0v;
                float x1 = acc[mt][1][r] + b1v;
                float x2 = acc[mt][2][r] + b2v;
                float x3 = acc[mt][3][r] + b3v;
                const float* ct = cosT + s * 64;
                const float* st = sinT + s * 64;
                float o0 = x0 * ct[lo]      - x2 * st[lo];
                float o1 = x1 * ct[16 + lo] - x3 * st[16 + lo];
                float o2 = x2 * ct[32 + lo] + x0 * st[32 + lo];
                float o3 = x3 * ct[48 + lo] + x1 * st[48 + lo];
                __bf16* row = dstb + ((size_t)(bidx * NH + h) * S_LEN + s) * 64;
                if (seg == 0) {
                    // SCALE*LOG2E so attention can use raw v_exp_f32 (2^x)
                    row[lo]      = (__bf16)(o0 * (SCALE * LOG2E));
                    row[16 + lo] = (__bf16)(o1 * (SCALE * LOG2E));
                    row[32 + lo] = (__bf16)(o2 * (SCALE * LOG2E));
                    row[48 + lo] = (__bf16)(o3 * (SCALE * LOG2E));
                } else {
                    const int rot = (s & 7) * 8;
                    row[(lo + rot) & 63]      = (__bf16)o0;
                    row[(16 + lo + rot) & 63] = (__bf16)o1;
                    row[(32 + lo + rot) & 63] = (__bf16)o2;
                    row[(48 + lo + rot) & 63] = (__bf16)o3;
                }
            }
        }
    } else {
        // v segment: chunked wave-private 64x64 transposes -> vT
        __syncthreads();
        const int h = ((n0 - 2048) >> 6) + wc;
        float bv4[4];
        bv4[0] = bias2[h * 64 + lo];
        bv4[1] = bias2[h * 64 + 16 + lo];
        bv4[2] = bias2[h * 64 + 32 + lo];
        bv4[3] = bias2[h * 64 + 48 + lo];
        __bf16* Treg = SMEM + w * 1088;       // 16 rows x 68 per wave
        const int rdrow = lane >> 2;          // 0..15
        const int rdcol = (lane & 3) * 16;    // 0,16,32,48
#pragma unroll
        for (int nt = 0; nt < 4; ++nt) {
#pragma unroll
            for (int mh = 0; mh < 2; ++mh) {
#pragma unroll
                for (int mt = 0; mt < 4; ++mt)
#pragma unroll
                    for (int r = 0; r < 4; ++r) {
                        const int tl = mt * 16 + quad * 4 + r;
                        const int li = (tl & 1) * 32 + (tl >> 1);
                        Treg[lo * 68 + li] = (__bf16)(acc[mh * 4 + mt][nt][r] + bv4[nt]);
                    }
                const int d = nt * 16 + rdrow;
                const int rot = (d & 7) * 8;
                const int bidx = rdcol >> 5;
                const int soff = rdcol & 31;
                bf16x8 v0 = *(const bf16x8*)&Treg[rdrow * 68 + rdcol];
                bf16x8 v1 = *(const bf16x8*)&Treg[rdrow * 68 + rdcol + 8];
                __bf16* base = vT + ((size_t)((bidx * NH + h) * 64 + d)) * S_LEN;
                const int sbase = (m0 >> 1) + wr * 64 + mh * 32;
                const int s0 = sbase + soff;
                const int s1 = s0 + 8;
                *(bf16x8*)(base + (s0 & ~63) + (((s0 & 63) + rot) & 63)) = v0;
                *(bf16x8*)(base + (s1 & ~63) + (((s1 & 63) + rot) & 63)) = v1;
            }
        }
    }
#undef ITER
#undef MFMA_Q
#undef READ_BF
#undef READ_AF
#undef STAGE_B
#undef STAGE_A
}

// ---------------------------------------------------------------------------
// Out-proj GEMM (unchanged): folded-RMSNorm epilogue.
// ---------------------------------------------------------------------------
__global__ __launch_bounds__(256) void gemm_out(const __bf16* __restrict__ A,
                                                const __bf16* __restrict__ W,
                                                const float* __restrict__ sumsq,
                                                float* __restrict__ outF) {
    __shared__ __bf16 As[128 * 64];
    __shared__ __bf16 Bs[128 * 64];

    const int tid  = threadIdx.x;
    const int w    = tid >> 6;
    const int lane = tid & 63;
    const int quad = lane >> 4;
    const int lo   = lane & 15;
    const int wr   = w >> 1;
    const int wc   = w & 1;
    const int m0 = blockIdx.y * 128;
    const int n0 = blockIdx.x * 128;
    const int K = EDIM;

    f32x4 acc[4][4];
#pragma unroll
    for (int i = 0; i < 4; ++i)
#pragma unroll
        for (int j = 0; j < 4; ++j) acc[i][j] = (f32x4){0.f, 0.f, 0.f, 0.f};

    const int srow = (lane >> 3);
    const int scol = (lane & 7) * 8;
    const int rotc = (lo & 7) * 8;

    for (int kt = 0; kt < K; kt += 64) {
        __syncthreads();
#pragma unroll
        for (int i = 0; i < 4; ++i) {
            const int r = w * 32 + i * 8;
            GLOAD_LDS16(A + (size_t)(m0 + r + srow) * K + kt + scol, &As[r * 64]);
            GLOAD_LDS16(W + (size_t)(n0 + r + srow) * K + kt + scol, &Bs[r * 64]);
        }
        __syncthreads();

#pragma unroll
        for (int kk = 0; kk < 2; ++kk) {
            const int cidx = (kk * 32 + quad * 8 + rotc) & 63;
            bf16x8 af[4], bf[4];
#pragma unroll
            for (int t = 0; t < 4; ++t) {
                af[t] = *(const bf16x8*)&As[(wr * 64 + t * 16 + lo) * 64 + cidx];
                bf[t] = *(const bf16x8*)&Bs[(wc * 64 + t * 16 + lo) * 64 + cidx];
            }
#pragma unroll
            for (int mt = 0; mt < 4; ++mt)
#pragma unroll
                for (int nt = 0; nt < 4; ++nt)
                    acc[mt][nt] = __builtin_amdgcn_mfma_f32_16x16x32_bf16(
                        af[mt], bf[nt], acc[mt][nt], 0, 0, 0);
        }
    }

    const int colbase = n0 + wc * 64;
#pragma unroll
    for (int mt = 0; mt < 4; ++mt) {
#pragma unroll
        for (int r = 0; r < 4; ++r) {
            const int row = m0 + wr * 64 + mt * 16 + quad * 4 + r;
            const float invr = rsqrtf(sumsq[row] * (1.0f / EDIM) + EPS);
            float* orow = outF + (size_t)row * EDIM;
#pragma unroll
            for (int nt = 0; nt < 4; ++nt)
                orow[colbase + nt * 16 + lo] = acc[mt][nt][r] * invr;
        }
    }
}

// ---------------------------------------------------------------------------
// Flash attention v12: v11's no-split-K finalize epilogue + 4 blocks/CU
// restored. ONE q-tile per block: grid 32 bh x 32 z = 1024 blocks — all
// co-resident (LDS 33.8 KB -> 4/CU). Block durations are (tile+1) iters
// (1..32); balance comes from the z->tile map  tile = z<16 ? z : 47-z :
// under round-robin CU assignment the 4 resident blocks on a CU have
// y-values {y0, y0+8, y0+16, y0+24} -> two complementary pairs {t,31-t}
// -> per-CU iteration sum == 66 for EVERY CU. Perf heuristic only; any
// assignment still computes correct results (guide §1). Body per K-tile
// identical to v10/v11 (K-dbuf, counted vmcnt, T5 setprio).
// ---------------------------------------------------------------------------
__global__ __launch_bounds__(256) void attn_v12(const __bf16* __restrict__ qb,
                                                const __bf16* __restrict__ kb,
                                                const __bf16* __restrict__ vT,
                                                __bf16* __restrict__ attnb,
                                                float* __restrict__ sumsq) {
    __shared__ __bf16 Ks[2][64 * 64];    // double-buffered K ([key][d'] rot)
    __shared__ __bf16 Vt[64 * 64];       // single-buffered V ([d][key'] rot)
    __shared__ __bf16 Ps[4][16][72];     // wave-private, padded

    const int tid  = threadIdx.x;
    const int w    = tid >> 6;
    const int lane = tid & 63;
    const int quad = lane >> 4;
    const int lo   = lane & 15;
    const int bh   = blockIdx.x;         // 0..31  (= bidx*NH + h)
    const int z    = blockIdx.y;         // 0..31
    const int tile = (z < 16) ? z : 47 - z;   // balanced-sum mapping
    const int bidx = bh >> 4;            // batch
    const int h    = bh & 15;            // head

    const __bf16* ktile0 = kb + (size_t)bh * S_LEN * 64 + tid * 8;
    const int vd0 = w * 16 + (lane >> 3);
    const __bf16* vsrc0 = vT + ((size_t)bh * 64 + vd0) * S_LEN + (lane & 7) * 8;
    const __bf16* vsrc1 = vsrc0 + 8 * S_LEN;

#define STAGE_K(buf, kt) do { \
    GLOAD_LDS16(ktile0 + (kt) * 4096,        &Ks[buf][tid * 8]); \
    GLOAD_LDS16(ktile0 + (kt) * 4096 + 2048, &Ks[buf][2048 + tid * 8]); } while (0)
#define STAGE_V(kt) do { \
    GLOAD_LDS16(vsrc0 + (kt) * 64, &Vt[vd0 * 64 + (lane & 7) * 8]); \
    GLOAD_LDS16(vsrc1 + (kt) * 64, &Vt[(vd0 + 8) * 64 + (lane & 7) * 8]); } while (0)
#define VMCNT(n) do { asm volatile("s_waitcnt vmcnt(" #n ")" ::: "memory"); \
                      __builtin_amdgcn_sched_barrier(0); } while (0)

#define QK_EXP(KSP, AQ0, AQ1, LACC, DIAG, AP0, AP1) do { \
    f32x4 sc[4]; \
    SETP(1); \
    _Pragma("unroll") for (int nt = 0; nt < 4; ++nt) { \
        const int krow = nt * 16 + lo; \
        const int rot  = krow & 7; \
        bf16x8 k0 = *(const bf16x8*)&(KSP)[krow * 64 + ((quad + rot) & 7) * 8]; \
        bf16x8 k1 = *(const bf16x8*)&(KSP)[krow * 64 + ((quad + 4 + rot) & 7) * 8]; \
        f32x4 cc = (f32x4){0.f, 0.f, 0.f, 0.f}; \
        cc = __builtin_amdgcn_mfma_f32_16x16x32_bf16(AQ0, k0, cc, 0, 0, 0); \
        cc = __builtin_amdgcn_mfma_f32_16x16x32_bf16(AQ1, k1, cc, 0, 0, 0); \
        sc[nt] = cc; } \
    SETP(0); \
    if (DIAG) { \
        _Pragma("unroll") for (int nt = 0; nt < 4; ++nt) \
        _Pragma("unroll") for (int r = 0; r < 4; ++r) \
            if (nt * 16 + lo > w * 16 + quad * 4 + r) sc[nt][r] = -1e30f; } \
    _Pragma("unroll") for (int nt = 0; nt < 4; ++nt) { \
        _Pragma("unroll") for (int r = 0; r < 4; ++r) { \
            float pv = __builtin_amdgcn_exp2f(sc[nt][r]); \
            LACC[r] += pv; \
            Ps[w][quad * 4 + r][nt * 16 + lo] = (__bf16)pv; } } \
    AP0 = *(const bf16x8*)&Ps[w][lo][quad * 8]; \
    AP1 = *(const bf16x8*)&Ps[w][lo][32 + quad * 8]; \
} while (0)

#define PV_ACC(AP0, AP1, OACC) do { \
    SETP(1); \
    _Pragma("unroll") for (int dt = 0; dt < 4; ++dt) { \
        const int vrow = dt * 16 + lo; \
        const int vrot = vrow & 7; \
        bf16x8 vb0 = *(const bf16x8*)&Vt[vrow * 64 + ((quad + vrot) & 7) * 8]; \
        bf16x8 vb1 = *(const bf16x8*)&Vt[vrow * 64 + ((quad + 4 + vrot) & 7) * 8]; \
        OACC[dt] = __builtin_amdgcn_mfma_f32_16x16x32_bf16(AP0, vb0, OACC[dt], 0, 0, 0); \
        OACC[dt] = __builtin_amdgcn_mfma_f32_16x16x32_bf16(AP1, vb1, OACC[dt], 0, 0, 0); } \
    SETP(0); \
} while (0)

    const int qrow_w = tile * 64 + w * 16;
    const __bf16* qrow = qb + ((size_t)bh * S_LEN + qrow_w + lo) * 64;
    bf16x8 aq0 = *(const bf16x8*)(qrow + quad * 8);
    bf16x8 aq1 = *(const bf16x8*)(qrow + 32 + quad * 8);

    float l_acc[4] = {0.f, 0.f, 0.f, 0.f};
    f32x4 o_acc[4];
#pragma unroll
    for (int dt = 0; dt < 4; ++dt) o_acc[dt] = (f32x4){0.f, 0.f, 0.f, 0.f};

    STAGE_K(0, 0);
    int cur = 0;
    int kt = 0;

    for (; kt + 1 <= tile; ++kt) {
        __builtin_amdgcn_s_barrier();          // prev Vt/Ks[cur^1] readers done
        STAGE_V(kt);
        STAGE_K(cur ^ 1, kt + 1);
        VMCNT(4);                              // own K(cur) landed (issued 1 iter ago)
        __builtin_amdgcn_s_barrier();          // Ks[cur] visible to all waves
        bf16x8 ap0, ap1;
        QK_EXP(Ks[cur], aq0, aq1, l_acc, false, ap0, ap1);
        VMCNT(2);                              // own V landed (hidden under QK)
        __builtin_amdgcn_s_barrier();          // Vt visible to all waves
        PV_ACC(ap0, ap1, o_acc);
        cur ^= 1;
    }
    // peeled final (diagonal) tile: no K-prefetch
    {
        __builtin_amdgcn_s_barrier();
        STAGE_V(kt);
        VMCNT(2);                              // own K(cur) landed
        __builtin_amdgcn_s_barrier();
        bf16x8 ap0, ap1;
        QK_EXP(Ks[cur], aq0, aq1, l_acc, true, ap0, ap1);
        VMCNT(0);                              // own V landed
        __builtin_amdgcn_s_barrier();
        PV_ACC(ap0, ap1, o_acc);
    }

    // --- epilogue: finalize (divide by complete l), write attnb in the
    // rotated GEMM-A layout, atomic per-row sumsq partial ---
#pragma unroll
    for (int r = 0; r < 4; ++r) {
        float lr = l_acc[r];
        lr += __shfl_xor(lr, 1, 64);
        lr += __shfl_xor(lr, 2, 64);
        lr += __shfl_xor(lr, 4, 64);
        lr += __shfl_xor(lr, 8, 64);
        const float inv = 1.0f / lr;
        const int sq = qrow_w + quad * 4 + r;
        const int token = sq * BATCH + bidx;
        const int rot = (token & 7) * 8;
        __bf16* trow = attnb + (size_t)token * EDIM + h * 64;
        float ssp = 0.f;
#pragma unroll
        for (int dt = 0; dt < 4; ++dt) {
            float o = o_acc[dt][r] * inv;
            ssp += o * o;
            trow[(dt * 16 + lo + rot) & 63] = (__bf16)o;
        }
        ssp += __shfl_xor(ssp, 1, 64);
        ssp += __shfl_xor(ssp, 2, 64);
        ssp += __shfl_xor(ssp, 4, 64);
        ssp += __shfl_xor(ssp, 8, 64);
        if (lo == 0) atomicAdd(&sumsq[token], ssp);
    }
#undef PV_ACC
#undef QK_EXP
#undef VMCNT
#undef STAGE_V
#undef STAGE_K
}

// ---------------------------------------------------------------------------
extern "C" void kernel_launch(void* const* d_in, const int* in_sizes, int n_in,
                              void* d_out, int out_size, void* d_ws, size_t ws_size,
                              hipStream_t stream) {
    const float* x    = (const float*)d_in[0];
    const float* cosT = (const float*)d_in[2];
    const float* sinT = (const float*)d_in[3];
    const float* Wq   = (const float*)d_in[4];
    const float* bq   = (const float*)d_in[5];
    const float* Wk   = (const float*)d_in[6];
    const float* bk   = (const float*)d_in[7];
    const float* Wv   = (const float*)d_in[8];
    const float* bv   = (const float*)d_in[9];
    const float* Wo   = (const float*)d_in[10];
    const float* nw   = (const float*)d_in[11];
    float* out = (float*)d_out;

    // Workspace (80 MiB): layout unchanged.
    char* wsb = (char*)d_ws;
    const size_t MB = 1024 * 1024;
    __bf16* qb     = (__bf16*)(wsb + 0 * MB);
    __bf16* attnb  = (__bf16*)(wsb + 8 * MB);
    float*  sumsq  = (float*)(wsb + 16 * MB);
    __bf16* xb     = (__bf16*)(wsb + 48 * MB);
    __bf16* kb     = (__bf16*)(wsb + 56 * MB);
    __bf16* vT     = (__bf16*)(wsb + 64 * MB);
    __bf16* Wqkvb  = (__bf16*)(wsb + 72 * MB);
    __bf16* Wob    = (__bf16*)(wsb + 78 * MB);

    cast_all<<<(8 * 1024 * 1024) / (256 * 8), 256, 0, stream>>>(
        x, Wq, Wk, Wv, Wo, nw, xb, Wqkvb, Wob, sumsq);

    // 256x256 8-phase QKV GEMM: 12x16 = 192 blocks, 512 threads, 128 KiB LDS
    gemm_qkv<<<dim3(3072 / 256, MTOK / 256), 512, 0, stream>>>(
        xb, Wqkvb, bq, bk, bv, qb, kb, vT, cosT, sinT);

    // one q-tile per block, balanced-sum mapping: 32 bh x 32 z = 1024 blocks
    attn_v12<<<dim3(BATCH * NH, 32), 256, 0, stream>>>(qb, kb, vT, attnb, sumsq);

    gemm_out<<<dim3(1024 / 128, MTOK / 128), 256, 0, stream>>>(
        attnb, Wob, sumsq, out);
}

// Round 11
// 206.474 us; speedup vs baseline: 1.0350x; 1.0350x over previous
//
#include <hip/hip_runtime.h>
#include <hip/hip_bf16.h>
#include <math.h>

#define S_LEN 2048
#define BATCH 2
#define EDIM 1024
#define NH 16
#define HD 64
#define MTOK (S_LEN * BATCH)   // 4096 tokens
#define SCALE 0.125f           // 64^-0.5
#define LOG2E 1.4426950408889634f
#define EPS 1e-6f

typedef __bf16 bf16x8 __attribute__((ext_vector_type(8)));
typedef __bf16 bf16x4 __attribute__((ext_vector_type(4)));
typedef float f32x4 __attribute__((ext_vector_type(4)));

typedef __attribute__((address_space(3))) void lds_void;
typedef const __attribute__((address_space(1))) void gbl_void;
#define GLOAD_LDS16(g, l) \
    __builtin_amdgcn_global_load_lds((gbl_void*)(g), (lds_void*)(l), 16, 0, 0)

// All bf16 GEMM operand buffers use the "row-rotation" layout: within each
// aligned 64-col block of row m, element at col c is stored at
// (c & ~63) | ((c + (m&7)*8) & 63). GEMM frag reads apply the inverse
// (rot=(lo&7)*8) -> LDS reads are 2-way (free, m136) instead of 16-way.

// ---------------------------------------------------------------------------
// cast_all (unchanged)
// ---------------------------------------------------------------------------
__global__ __launch_bounds__(256) void cast_all(const float* __restrict__ x,
                                                const float* __restrict__ Wq,
                                                const float* __restrict__ Wk,
                                                const float* __restrict__ Wv,
                                                const float* __restrict__ Wo,
                                                const float* __restrict__ nw,
                                                __bf16* __restrict__ xb,
                                                __bf16* __restrict__ Wqkvb,
                                                __bf16* __restrict__ Wob,
                                                float* __restrict__ sumsq) {
    int gt = blockIdx.x * 256 + threadIdx.x;
    if (gt < 1024) ((float4*)sumsq)[gt] = (float4){0.f, 0.f, 0.f, 0.f};
    int i = gt * 8;

    const float* src;
    __bf16* dstbase;
    int row, c;
    bool isWo = false;
    if (i < (MTOK * EDIM)) {
        src = x + i;
        row = i >> 10; c = i & 1023;
        dstbase = xb + ((size_t)row << 10);
    } else {
        int j = i - MTOK * EDIM;
        int seg = j >> 20;
        int off = j & 0xFFFFF;
        src = ((seg == 0) ? Wq : (seg == 1) ? Wk : (seg == 2) ? Wv : Wo) + off;
        row = off >> 10; c = off & 1023;
        if (seg < 3) { dstbase = Wqkvb + ((size_t)(j >> 10) << 10); }
        else         { dstbase = Wob + ((size_t)row << 10); isWo = true; }
    }
    float4 a = *(const float4*)(src);
    float4 b = *(const float4*)(src + 4);
    if (isWo) {
        float4 na = *(const float4*)(nw + c);
        float4 nb = *(const float4*)(nw + c + 4);
        a.x *= na.x; a.y *= na.y; a.z *= na.z; a.w *= na.w;
        b.x *= nb.x; b.y *= nb.y; b.z *= nb.z; b.w *= nb.w;
    }
    bf16x8 o;
    o[0] = (__bf16)a.x; o[1] = (__bf16)a.y; o[2] = (__bf16)a.z; o[3] = (__bf16)a.w;
    o[4] = (__bf16)b.x; o[5] = (__bf16)b.y; o[6] = (__bf16)b.z; o[7] = (__bf16)b.w;
    int rot = (row & 7) * 8;
    int cp = (c & ~63) | ((c + rot) & 63);
    *(bf16x8*)(dstbase + cp) = o;
}

// ---------------------------------------------------------------------------
// QKV GEMM v2 (unchanged from R2): 256x256 8-phase counted-vmcnt; q epilogue
// folds LOG2E into SCALE so attention uses raw v_exp_f32 (2^x).
// ---------------------------------------------------------------------------
#define BARRIER __builtin_amdgcn_s_barrier()
#define LGKM0 do { asm volatile("s_waitcnt lgkmcnt(0)" ::: "memory"); \
                   __builtin_amdgcn_sched_barrier(0); } while (0)
#define SETP(x) __builtin_amdgcn_s_setprio(x)

__global__ __launch_bounds__(512, 2) void gemm_qkv(const __bf16* __restrict__ A,
                                                   const __bf16* __restrict__ W,
                                                   const float* __restrict__ bias0,
                                                   const float* __restrict__ bias1,
                                                   const float* __restrict__ bias2,
                                                   __bf16* __restrict__ qb,
                                                   __bf16* __restrict__ kb,
                                                   __bf16* __restrict__ vT,
                                                   const float* __restrict__ cosT,
                                                   const float* __restrict__ sinT) {
    // [buf0.A 256x64 | buf0.B 256x64 | buf1.A 256x64 | buf1.B 256x64]
    __shared__ __bf16 SMEM[4 * 256 * 64];   // 128 KiB

    const int tid  = threadIdx.x;
    const int w    = tid >> 6;       // 0..7
    const int lane = tid & 63;
    const int quad = lane >> 4;
    const int lo   = lane & 15;
    const int wr   = w >> 2;         // M-wave 0..1 (128 rows each)
    const int wc   = w & 3;          // N-wave 0..3 (64 cols each = one head)
    const int m0 = blockIdx.y * 256;
    const int n0 = blockIdx.x * 256;

    f32x4 acc[8][4];
#pragma unroll
    for (int i = 0; i < 8; ++i)
#pragma unroll
        for (int j = 0; j < 4; ++j) acc[i][j] = (f32x4){0.f, 0.f, 0.f, 0.f};

    // staging: 512 threads, lane-linear LDS dest (wave-uniform base + lane*16)
    const int srow = tid >> 3;            // 0..63
    const int scol = (tid & 7) * 8;       // 0..56
    const __bf16* Ag = A + (size_t)(m0 + srow) * EDIM + scol;
    const __bf16* Bg = W + (size_t)(n0 + srow) * EDIM + scol;
    __bf16* ldsA0 = SMEM + srow * 64 + scol;
    __bf16* ldsB0 = SMEM + 16384 + srow * 64 + scol;

#define STAGE_A(b, h, kt) do { \
    GLOAD_LDS16(Ag + (size_t)((h) * 131072 + (kt) * 64),         ldsA0 + (b) * 32768 + (h) * 8192); \
    GLOAD_LDS16(Ag + (size_t)((h) * 131072 + 65536 + (kt) * 64), ldsA0 + (b) * 32768 + (h) * 8192 + 4096); } while (0)
#define STAGE_B(b, h, kt) do { \
    GLOAD_LDS16(Bg + (size_t)((h) * 131072 + (kt) * 64),         ldsB0 + (b) * 32768 + (h) * 8192); \
    GLOAD_LDS16(Bg + (size_t)((h) * 131072 + 65536 + (kt) * 64), ldsB0 + (b) * 32768 + (h) * 8192 + 4096); } while (0)

    // fragment reads (inverse row-rotation; row&7 == lo&7 since bases %16==0)
    const int rotc = (lo & 7) * 8;
    const int c0 = (quad * 8 + rotc) & 63;          // kk=0
    const int c1 = (32 + quad * 8 + rotc) & 63;     // kk=1
    const __bf16* Arow = SMEM + (wr * 128 + lo) * 64;
    const __bf16* Brow = SMEM + 16384 + (wc * 64 + lo) * 64;

    bf16x8 af[4][2], bf0[2][2], bf1[2][2];

#define READ_AF(b, mh) do { _Pragma("unroll") for (int i = 0; i < 4; ++i) { \
    af[i][0] = *(const bf16x8*)&Arow[(b) * 32768 + ((mh) * 4 + i) * 1024 + c0]; \
    af[i][1] = *(const bf16x8*)&Arow[(b) * 32768 + ((mh) * 4 + i) * 1024 + c1]; } } while (0)
#define READ_BF(b, nh, dst) do { _Pragma("unroll") for (int j = 0; j < 2; ++j) { \
    dst[j][0] = *(const bf16x8*)&Brow[(b) * 32768 + ((nh) * 2 + j) * 1024 + c0]; \
    dst[j][1] = *(const bf16x8*)&Brow[(b) * 32768 + ((nh) * 2 + j) * 1024 + c1]; } } while (0)

#define MFMA_Q(mh, nh, BF) do { \
    _Pragma("unroll") for (int i = 0; i < 4; ++i) \
    _Pragma("unroll") for (int j = 0; j < 2; ++j) { \
        acc[(mh)*4+i][(nh)*2+j] = __builtin_amdgcn_mfma_f32_16x16x32_bf16( \
            af[i][0], BF[j][0], acc[(mh)*4+i][(nh)*2+j], 0, 0, 0); \
        acc[(mh)*4+i][(nh)*2+j] = __builtin_amdgcn_mfma_f32_16x16x32_bf16( \
            af[i][1], BF[j][1], acc[(mh)*4+i][(nh)*2+j], 0, 0, 0); } } while (0)

#define ITER(ST, T0) do { \
    /* P1: quadrant (mh0,nh0) of tile T0 (buf0) */ \
    READ_AF(0, 0); READ_BF(0, 0, bf0); \
    BARRIER; LGKM0; SETP(1); MFMA_Q(0, 0, bf0); SETP(0); BARRIER; \
    /* P2: (mh0,nh1) */ \
    READ_BF(0, 1, bf1); \
    BARRIER; LGKM0; SETP(1); MFMA_Q(0, 1, bf1); SETP(0); BARRIER; \
    /* P3: (mh1,nh1); stage B0(T0+2) */ \
    READ_AF(0, 1); \
    if (ST) STAGE_B(0, 0, (T0) + 2); \
    BARRIER; LGKM0; SETP(1); MFMA_Q(1, 1, bf1); SETP(0); BARRIER; \
    /* P4: (mh1,nh0); stage B1,A0(T0+2); counted vmcnt */ \
    if (ST) { STAGE_B(0, 1, (T0) + 2); STAGE_A(0, 0, (T0) + 2); } \
    BARRIER; SETP(1); MFMA_Q(1, 0, bf0); SETP(0); \
    if (ST) { asm volatile("s_waitcnt vmcnt(6)" ::: "memory"); } \
    else    { asm volatile("s_waitcnt vmcnt(0)" ::: "memory"); } \
    BARRIER; \
    /* P5: (mh0,nh0) of tile T0+1 (buf1); stage A1(T0+2) */ \
    READ_AF(1, 0); READ_BF(1, 0, bf0); \
    if (ST) STAGE_A(0, 1, (T0) + 2); \
    BARRIER; LGKM0; SETP(1); MFMA_Q(0, 0, bf0); SETP(0); BARRIER; \
    /* P6: (mh0,nh1) */ \
    READ_BF(1, 1, bf1); \
    BARRIER; LGKM0; SETP(1); MFMA_Q(0, 1, bf1); SETP(0); BARRIER; \
    /* P7: (mh1,nh1); stage B0(T0+3) */ \
    READ_AF(1, 1); \
    if (ST) STAGE_B(1, 0, (T0) + 3); \
    BARRIER; LGKM0; SETP(1); MFMA_Q(1, 1, bf1); SETP(0); BARRIER; \
    /* P8: (mh1,nh0); stage B1,A0,A1(T0+3); counted vmcnt */ \
    if (ST) { STAGE_B(1, 1, (T0) + 3); STAGE_A(1, 0, (T0) + 3); STAGE_A(1, 1, (T0) + 3); } \
    BARRIER; SETP(1); MFMA_Q(1, 0, bf0); SETP(0); \
    if (ST) { asm volatile("s_waitcnt vmcnt(8)" ::: "memory"); } \
    BARRIER; \
} while (0)

    // prologue: tile0 -> buf0 (oldest 8 loads), tile1 -> buf1; keep tile1 in flight
    STAGE_A(0, 0, 0); STAGE_A(0, 1, 0); STAGE_B(0, 0, 0); STAGE_B(0, 1, 0);
    STAGE_A(1, 0, 1); STAGE_A(1, 1, 1); STAGE_B(1, 0, 1); STAGE_B(1, 1, 1);
    asm volatile("s_waitcnt vmcnt(8)" ::: "memory");
    BARRIER;

#pragma unroll 1
    for (int p = 0; p < 7; ++p) { ITER(1, 2 * p); }
    ITER(0, 14);

    // ------------------------- epilogues -------------------------
    const int seg = n0 >> 10;                 // block-uniform (256 | 1024)
    const int colbase = (n0 & 1023) + wc * 64;

    if (seg < 2) {
        // fused RoPE: wave covers one head (64 cols)
        const float* bp = (seg == 0) ? bias0 : bias1;
        __bf16* dstb = (seg == 0) ? qb : kb;
        const int h = colbase >> 6;
        float b0v = bp[colbase + lo];
        float b1v = bp[colbase + 16 + lo];
        float b2v = bp[colbase + 32 + lo];
        float b3v = bp[colbase + 48 + lo];
#pragma unroll
        for (int mt = 0; mt < 8; ++mt) {
#pragma unroll
            for (int r = 0; r < 4; ++r) {
                const int m = m0 + wr * 128 + mt * 16 + quad * 4 + r;
                const int s = m >> 1, bidx = m & 1;
                float x0 = acc[mt][0][r] + b0v;
                float x1 = acc[mt][1][r] + b1v;
                float x2 = acc[mt][2][r] + b2v;
                float x3 = acc[mt][3][r] + b3v;
                const float* ct = cosT + s * 64;
                const float* st = sinT + s * 64;
                float o0 = x0 * ct[lo]      - x2 * st[lo];
                float o1 = x1 * ct[16 + lo] - x3 * st[16 + lo];
                float o2 = x2 * ct[32 + lo] + x0 * st[32 + lo];
                float o3 = x3 * ct[48 + lo] + x1 * st[48 + lo];
                __bf16* row = dstb + ((size_t)(bidx * NH + h) * S_LEN + s) * 64;
                if (seg == 0) {
                    // SCALE*LOG2E so attention can use raw v_exp_f32 (2^x)
                    row[lo]      = (__bf16)(o0 * (SCALE * LOG2E));
                    row[16 + lo] = (__bf16)(o1 * (SCALE * LOG2E));
                    row[32 + lo] = (__bf16)(o2 * (SCALE * LOG2E));
                    row[48 + lo] = (__bf16)(o3 * (SCALE * LOG2E));
                } else {
                    const int rot = (s & 7) * 8;
                    row[(lo + rot) & 63]      = (__bf16)o0;
                    row[(16 + lo + rot) & 63] = (__bf16)o1;
                    row[(32 + lo + rot) & 63] = (__bf16)o2;
                    row[(48 + lo + rot) & 63] = (__bf16)o3;
                }
            }
        }
    } else {
        // v segment: chunked wave-private 64x64 transposes -> vT
        __syncthreads();
        const int h = ((n0 - 2048) >> 6) + wc;
        float bv4[4];
        bv4[0] = bias2[h * 64 + lo];
        bv4[1] = bias2[h * 64 + 16 + lo];
        bv4[2] = bias2[h * 64 + 32 + lo];
        bv4[3] = bias2[h * 64 + 48 + lo];
        __bf16* Treg = SMEM + w * 1088;       // 16 rows x 68 per wave
        const int rdrow = lane >> 2;          // 0..15
        const int rdcol = (lane & 3) * 16;    // 0,16,32,48
#pragma unroll
        for (int nt = 0; nt < 4; ++nt) {
#pragma unroll
            for (int mh = 0; mh < 2; ++mh) {
#pragma unroll
                for (int mt = 0; mt < 4; ++mt)
#pragma unroll
                    for (int r = 0; r < 4; ++r) {
                        const int tl = mt * 16 + quad * 4 + r;
                        const int li = (tl & 1) * 32 + (tl >> 1);
                        Treg[lo * 68 + li] = (__bf16)(acc[mh * 4 + mt][nt][r] + bv4[nt]);
                    }
                const int d = nt * 16 + rdrow;
                const int rot = (d & 7) * 8;
                const int bidx = rdcol >> 5;
                const int soff = rdcol & 31;
                bf16x8 v0 = *(const bf16x8*)&Treg[rdrow * 68 + rdcol];
                bf16x8 v1 = *(const bf16x8*)&Treg[rdrow * 68 + rdcol + 8];
                __bf16* base = vT + ((size_t)((bidx * NH + h) * 64 + d)) * S_LEN;
                const int sbase = (m0 >> 1) + wr * 64 + mh * 32;
                const int s0 = sbase + soff;
                const int s1 = s0 + 8;
                *(bf16x8*)(base + (s0 & ~63) + (((s0 & 63) + rot) & 63)) = v0;
                *(bf16x8*)(base + (s1 & ~63) + (((s1 & 63) + rot) & 63)) = v1;
            }
        }
    }
#undef ITER
#undef MFMA_Q
#undef READ_BF
#undef READ_AF
#undef STAGE_B
#undef STAGE_A
}

// ---------------------------------------------------------------------------
// Out-proj GEMM (R6/R8 version): folded-RMSNorm epilogue.
// ---------------------------------------------------------------------------
__global__ __launch_bounds__(256) void gemm_out(const __bf16* __restrict__ A,
                                                const __bf16* __restrict__ W,
                                                const float* __restrict__ sumsq,
                                                float* __restrict__ outF) {
    __shared__ __bf16 As[128 * 64];
    __shared__ __bf16 Bs[128 * 64];

    const int tid  = threadIdx.x;
    const int w    = tid >> 6;
    const int lane = tid & 63;
    const int quad = lane >> 4;
    const int lo   = lane & 15;
    const int wr   = w >> 1;
    const int wc   = w & 1;
    const int m0 = blockIdx.y * 128;
    const int n0 = blockIdx.x * 128;
    const int K = EDIM;

    f32x4 acc[4][4];
#pragma unroll
    for (int i = 0; i < 4; ++i)
#pragma unroll
        for (int j = 0; j < 4; ++j) acc[i][j] = (f32x4){0.f, 0.f, 0.f, 0.f};

    const int srow = (lane >> 3);
    const int scol = (lane & 7) * 8;
    const int rotc = (lo & 7) * 8;

    for (int kt = 0; kt < K; kt += 64) {
        __syncthreads();
#pragma unroll
        for (int i = 0; i < 4; ++i) {
            const int r = w * 32 + i * 8;
            GLOAD_LDS16(A + (size_t)(m0 + r + srow) * K + kt + scol, &As[r * 64]);
            GLOAD_LDS16(W + (size_t)(n0 + r + srow) * K + kt + scol, &Bs[r * 64]);
        }
        __syncthreads();

#pragma unroll
        for (int kk = 0; kk < 2; ++kk) {
            const int cidx = (kk * 32 + quad * 8 + rotc) & 63;
            bf16x8 af[4], bf[4];
#pragma unroll
            for (int t = 0; t < 4; ++t) {
                af[t] = *(const bf16x8*)&As[(wr * 64 + t * 16 + lo) * 64 + cidx];
                bf[t] = *(const bf16x8*)&Bs[(wc * 64 + t * 16 + lo) * 64 + cidx];
            }
#pragma unroll
            for (int mt = 0; mt < 4; ++mt)
#pragma unroll
                for (int nt = 0; nt < 4; ++nt)
                    acc[mt][nt] = __builtin_amdgcn_mfma_f32_16x16x32_bf16(
                        af[mt], bf[nt], acc[mt][nt], 0, 0, 0);
        }
    }

    const int colbase = n0 + wc * 64;
#pragma unroll
    for (int mt = 0; mt < 4; ++mt) {
#pragma unroll
        for (int r = 0; r < 4; ++r) {
            const int row = m0 + wr * 64 + mt * 16 + quad * 4 + r;
            const float invr = rsqrtf(sumsq[row] * (1.0f / EDIM) + EPS);
            float* orow = outF + (size_t)row * EDIM;
#pragma unroll
            for (int nt = 0; nt < 4; ++nt)
                orow[colbase + nt * 16 + lo] = acc[mt][nt][r] * invr;
        }
    }
}

// ---------------------------------------------------------------------------
// Flash attention v10b (R8 best-measured version): two-pass uniform-duration
// pairs {p, 31-p} with key-parity split-K, K-only double buffer, counted
// vmcnt, T5 setprio around both MFMA clusters, raw-exp2 softmax.
// ---------------------------------------------------------------------------
__global__ __launch_bounds__(256) void attn_v10(const __bf16* __restrict__ qb,
                                                const __bf16* __restrict__ kb,
                                                const __bf16* __restrict__ vT,
                                                __bf16* __restrict__ Opart,
                                                float* __restrict__ lpart) {
    __shared__ __bf16 Ks[2][64 * 64];    // double-buffered K ([key][d'] rot)
    __shared__ __bf16 Vt[64 * 64];       // single-buffered V ([d][key'] rot)
    __shared__ __bf16 Ps[4][16][72];     // wave-private, padded

    const int tid  = threadIdx.x;
    const int w    = tid >> 6;
    const int lane = tid & 63;
    const int quad = lane >> 4;
    const int lo   = lane & 15;
    const int bh   = blockIdx.x;         // 0..31
    const int z    = blockIdx.y;         // 0..31
    const int p    = z >> 1;             // pair 0..15
    const int hf   = z & 1;              // key-parity half

    const __bf16* ktile0 = kb + (size_t)bh * S_LEN * 64 + tid * 8;
    const int vd0 = w * 16 + (lane >> 3);
    const __bf16* vsrc0 = vT + ((size_t)bh * 64 + vd0) * S_LEN + (lane & 7) * 8;
    const __bf16* vsrc1 = vsrc0 + 8 * S_LEN;

#define STAGE_K(buf, kt) do { \
    GLOAD_LDS16(ktile0 + (kt) * 4096,        &Ks[buf][tid * 8]); \
    GLOAD_LDS16(ktile0 + (kt) * 4096 + 2048, &Ks[buf][2048 + tid * 8]); } while (0)
#define STAGE_V(kt) do { \
    GLOAD_LDS16(vsrc0 + (kt) * 64, &Vt[vd0 * 64 + (lane & 7) * 8]); \
    GLOAD_LDS16(vsrc1 + (kt) * 64, &Vt[(vd0 + 8) * 64 + (lane & 7) * 8]); } while (0)
#define VMCNT(n) do { asm volatile("s_waitcnt vmcnt(" #n ")" ::: "memory"); \
                      __builtin_amdgcn_sched_barrier(0); } while (0)

#define QK_EXP(KSP, AQ0, AQ1, LACC, DIAG, AP0, AP1) do { \
    f32x4 sc[4]; \
    SETP(1); \
    _Pragma("unroll") for (int nt = 0; nt < 4; ++nt) { \
        const int krow = nt * 16 + lo; \
        const int rot  = krow & 7; \
        bf16x8 k0 = *(const bf16x8*)&(KSP)[krow * 64 + ((quad + rot) & 7) * 8]; \
        bf16x8 k1 = *(const bf16x8*)&(KSP)[krow * 64 + ((quad + 4 + rot) & 7) * 8]; \
        f32x4 cc = (f32x4){0.f, 0.f, 0.f, 0.f}; \
        cc = __builtin_amdgcn_mfma_f32_16x16x32_bf16(AQ0, k0, cc, 0, 0, 0); \
        cc = __builtin_amdgcn_mfma_f32_16x16x32_bf16(AQ1, k1, cc, 0, 0, 0); \
        sc[nt] = cc; } \
    SETP(0); \
    if (DIAG) { \
        _Pragma("unroll") for (int nt = 0; nt < 4; ++nt) \
        _Pragma("unroll") for (int r = 0; r < 4; ++r) \
            if (nt * 16 + lo > w * 16 + quad * 4 + r) sc[nt][r] = -1e30f; } \
    _Pragma("unroll") for (int nt = 0; nt < 4; ++nt) { \
        _Pragma("unroll") for (int r = 0; r < 4; ++r) { \
            float pv = __builtin_amdgcn_exp2f(sc[nt][r]); \
            LACC[r] += pv; \
            Ps[w][quad * 4 + r][nt * 16 + lo] = (__bf16)pv; } } \
    AP0 = *(const bf16x8*)&Ps[w][lo][quad * 8]; \
    AP1 = *(const bf16x8*)&Ps[w][lo][32 + quad * 8]; \
} while (0)

#define PV_ACC(AP0, AP1, OACC) do { \
    SETP(1); \
    _Pragma("unroll") for (int dt = 0; dt < 4; ++dt) { \
        const int vrow = dt * 16 + lo; \
        const int vrot = vrow & 7; \
        bf16x8 vb0 = *(const bf16x8*)&Vt[vrow * 64 + ((quad + vrot) & 7) * 8]; \
        bf16x8 vb1 = *(const bf16x8*)&Vt[vrow * 64 + ((quad + 4 + vrot) & 7) * 8]; \
        OACC[dt] = __builtin_amdgcn_mfma_f32_16x16x32_bf16(AP0, vb0, OACC[dt], 0, 0, 0); \
        OACC[dt] = __builtin_amdgcn_mfma_f32_16x16x32_bf16(AP1, vb1, OACC[dt], 0, 0, 0); } \
    SETP(0); \
} while (0)

#pragma unroll
    for (int ti = 0; ti < 2; ++ti) {
        const int tile = ti ? (31 - p) : p;
        const int qrow_w = tile * 64 + w * 16;

        const __bf16* qrow = qb + ((size_t)bh * S_LEN + qrow_w + lo) * 64;
        bf16x8 aq0 = *(const bf16x8*)(qrow + quad * 8);
        bf16x8 aq1 = *(const bf16x8*)(qrow + 32 + quad * 8);

        float l_acc[4] = {0.f, 0.f, 0.f, 0.f};
        f32x4 o_acc[4];
#pragma unroll
        for (int dt = 0; dt < 4; ++dt) o_acc[dt] = (f32x4){0.f, 0.f, 0.f, 0.f};

        __builtin_amdgcn_s_barrier();
        if (hf <= tile) STAGE_K(0, hf);
        int cur = 0;
        int kt = hf;

        for (; kt + 2 <= tile; kt += 2) {
            __builtin_amdgcn_s_barrier();          // prev Vt/Ks[cur^1] readers done
            STAGE_V(kt);
            STAGE_K(cur ^ 1, kt + 2);
            VMCNT(4);                              // own K(cur) landed (issued 1 iter ago)
            __builtin_amdgcn_s_barrier();          // Ks[cur] visible to all waves
            bf16x8 ap0, ap1;
            QK_EXP(Ks[cur], aq0, aq1, l_acc, false, ap0, ap1);
            VMCNT(2);                              // own V landed (hidden under QK)
            __builtin_amdgcn_s_barrier();          // Vt visible to all waves
            PV_ACC(ap0, ap1, o_acc);
            cur ^= 1;
        }
        if (kt <= tile) {
            __builtin_amdgcn_s_barrier();
            STAGE_V(kt);
            VMCNT(2);                              // own K(cur) landed
            __builtin_amdgcn_s_barrier();
            bf16x8 ap0, ap1;
            const bool dg = (kt == tile);
            QK_EXP(Ks[cur], aq0, aq1, l_acc, dg, ap0, ap1);
            VMCNT(0);                              // own V landed
            __builtin_amdgcn_s_barrier();
            PV_ACC(ap0, ap1, o_acc);
        }

        // --- epilogue: raw partial O (bf16) + partial l; no division ---
#pragma unroll
        for (int r = 0; r < 4; ++r) {
            float lr = l_acc[r];
            lr += __shfl_xor(lr, 1, 64);
            lr += __shfl_xor(lr, 2, 64);
            lr += __shfl_xor(lr, 4, 64);
            lr += __shfl_xor(lr, 8, 64);
            const int sq = qrow_w + quad * 4 + r;
            __bf16* orow = Opart + ((size_t)(hf * 32 + bh) * S_LEN + sq) * 64;
#pragma unroll
            for (int dt = 0; dt < 4; ++dt)
                orow[dt * 16 + lo] = (__bf16)o_acc[dt][r];
            if (lo == 0) lpart[(size_t)(hf * 32 + bh) * S_LEN + sq] = lr;
        }
    }
#undef PV_ACC
#undef QK_EXP
#undef VMCNT
#undef STAGE_V
#undef STAGE_K
}

// ---------------------------------------------------------------------------
// combine (R6/R8 version)
// ---------------------------------------------------------------------------
__global__ __launch_bounds__(256) void combine(const __bf16* __restrict__ Opart,
                                               const float* __restrict__ lpart,
                                               __bf16* __restrict__ attnb,
                                               float* __restrict__ sumsq) {
    __shared__ float red[4];
    const int token = blockIdx.x;
    const int b = token & 1, s = token >> 1;
    const int t = threadIdx.x;
    const int h = t >> 4;
    const int d = (t * 4) & 63;
    const int bh = b * NH + h;

    size_t i0 = ((size_t)bh * S_LEN + s) * 64 + d;
    size_t i1 = ((size_t)(32 + bh) * S_LEN + s) * 64 + d;
    bf16x4 a0 = *(const bf16x4*)(Opart + i0);
    bf16x4 a1 = *(const bf16x4*)(Opart + i1);
    float l = lpart[(size_t)bh * S_LEN + s] + lpart[(size_t)(32 + bh) * S_LEN + s];
    float inv = 1.f / l;
    float o0 = ((float)a0[0] + (float)a1[0]) * inv;
    float o1 = ((float)a0[1] + (float)a1[1]) * inv;
    float o2 = ((float)a0[2] + (float)a1[2]) * inv;
    float o3 = ((float)a0[3] + (float)a1[3]) * inv;

    float ss = o0 * o0 + o1 * o1 + o2 * o2 + o3 * o3;
#pragma unroll
    for (int o = 32; o; o >>= 1) ss += __shfl_xor(ss, o, 64);
    if ((t & 63) == 0) red[t >> 6] = ss;
    __syncthreads();
    if (t == 0) sumsq[token] = red[0] + red[1] + red[2] + red[3];

    bf16x4 ov;
    ov[0] = (__bf16)o0; ov[1] = (__bf16)o1;
    ov[2] = (__bf16)o2; ov[3] = (__bf16)o3;
    const int c = t * 4;
    const int rot = (token & 7) * 8;
    const int cp = (c & ~63) | ((c + rot) & 63);
    *(bf16x4*)(attnb + (size_t)token * EDIM + cp) = ov;
}

// ---------------------------------------------------------------------------
extern "C" void kernel_launch(void* const* d_in, const int* in_sizes, int n_in,
                              void* d_out, int out_size, void* d_ws, size_t ws_size,
                              hipStream_t stream) {
    const float* x    = (const float*)d_in[0];
    const float* cosT = (const float*)d_in[2];
    const float* sinT = (const float*)d_in[3];
    const float* Wq   = (const float*)d_in[4];
    const float* bq   = (const float*)d_in[5];
    const float* Wk   = (const float*)d_in[6];
    const float* bk   = (const float*)d_in[7];
    const float* Wv   = (const float*)d_in[8];
    const float* bv   = (const float*)d_in[9];
    const float* Wo   = (const float*)d_in[10];
    const float* nw   = (const float*)d_in[11];
    float* out = (float*)d_out;

    // Workspace (80 MiB): R8 layout.
    char* wsb = (char*)d_ws;
    const size_t MB = 1024 * 1024;
    __bf16* qb     = (__bf16*)(wsb + 0 * MB);
    __bf16* attnb  = (__bf16*)(wsb + 8 * MB);
    float*  sumsq  = (float*)(wsb + 16 * MB);
    __bf16* Opart  = (__bf16*)(wsb + 17 * MB);
    float*  lpart  = (float*)(wsb + 33 * MB);
    __bf16* xb     = (__bf16*)(wsb + 48 * MB);
    __bf16* kb     = (__bf16*)(wsb + 56 * MB);
    __bf16* vT     = (__bf16*)(wsb + 64 * MB);
    __bf16* Wqkvb  = (__bf16*)(wsb + 72 * MB);
    __bf16* Wob    = (__bf16*)(wsb + 78 * MB);

    cast_all<<<(8 * 1024 * 1024) / (256 * 8), 256, 0, stream>>>(
        x, Wq, Wk, Wv, Wo, nw, xb, Wqkvb, Wob, sumsq);

    // 256x256 8-phase QKV GEMM: 12x16 = 192 blocks, 512 threads, 128 KiB LDS
    gemm_qkv<<<dim3(3072 / 256, MTOK / 256), 512, 0, stream>>>(
        xb, Wqkvb, bq, bk, bv, qb, kb, vT, cosT, sinT);

    // uniform-duration split-K attention, K-dbuf pipelined, T5 setprio
    attn_v10<<<dim3(BATCH * NH, 32), 256, 0, stream>>>(qb, kb, vT, Opart, lpart);

    combine<<<MTOK, 256, 0, stream>>>(Opart, lpart, attnb, sumsq);

    gemm_out<<<dim3(1024 / 128, MTOK / 128), 256, 0, stream>>>(
        attnb, Wob, sumsq, out);
}